// Round 1
// baseline (36825.146 us; speedup 1.0000x reference)
//
#include <hip/hip_runtime.h>

typedef unsigned short u16;
typedef __bf16 bf16x8 __attribute__((ext_vector_type(8)));
typedef float f32x4 __attribute__((ext_vector_type(4)));

constexpr int kB = 64;       // batch
constexpr int kT = 1024;     // timesteps
constexpr int kD = 512;      // input dim
constexpr int kU = 1024;     // hidden units
constexpr int kK = kD + kU;  // 1536 total contraction
constexpr int kNG = 256;     // workgroups == column groups (4 u each)
constexpr int kNC = 16;      // gate columns per WG (4 u * 4 gates)

// ---- workspace layout (bytes) ----
constexpr size_t OFF_BAR = 0;                                  // 2 u32 barrier state
constexpr size_t OFF_H   = 1024;                               // double-buffered h, bf16 [2][B][U]
constexpr size_t OFF_W   = OFF_H + 2ull * kB * kU * 2;         // permuted W bf16 [NG][K][NC]
constexpr size_t OFF_X   = OFF_W + (size_t)kNG * kK * kNC * 2; // x bf16 [T][B][D]
constexpr size_t WS_NEED = OFF_X + (size_t)kT * kB * kD * 2;   // ~76 MB total

// ---------- prologue: permute + bf16-convert weights ----------
// Wperm[g][k][c] = kernel[k][ (c>>2)*U + g*4 + (c&3) ]
__global__ void prep_w(const float* __restrict__ kern, u16* __restrict__ wperm) {
    const int g = blockIdx.x;
    const int c = threadIdx.x & 15;
    const int k = blockIdx.y * 16 + (threadIdx.x >> 4);
    const int gate = c >> 2, uu = c & 3;
    float v = kern[(size_t)k * (4 * kU) + gate * kU + g * 4 + uu];
    __bf16 b = (__bf16)v;
    wperm[((size_t)g * kK + k) * kNC + c] = *(u16*)&b;
}

// ---------- prologue: transpose + bf16-convert inputs ----------
// xbf[t][b][d] = bf16(inputs[b][t][d])
__global__ void prep_x(const float* __restrict__ inp, u16* __restrict__ xbf) {
    const int idx = blockIdx.x * 256 + threadIdx.x;   // < T*B*D = 33554432
    const int d = idx & (kD - 1);
    const int r = idx >> 9;
    const int b = r & (kB - 1);
    const int t = r >> 6;
    float v = inp[((size_t)b * kT + t) * kD + d];
    __bf16 bb = (__bf16)v;
    xbf[idx] = *(u16*)&bb;
}

// ---------- persistent LSTM kernel ----------
// grid = 256 WGs (one per CU), block = 1024 threads (16 waves).
// wave wid: mt = wid&3 (16-row batch tile), kg = wid>>2 (384-wide K slice).
__global__ __launch_bounds__(1024) void lstm_persist(
        const u16* __restrict__ wperm,
        const u16* __restrict__ xbf,
        u16* __restrict__ hbuf,
        const float* __restrict__ bias,
        float* __restrict__ out,
        unsigned* __restrict__ barv)   // barv[0]=cnt, barv[1]=epoch
{
    __shared__ float part[4][64][17];  // [kg][m][c], +1 pad vs bank conflicts
    __shared__ float cst[64][4];       // cell state c[m][uu], persistent in LDS
    __shared__ float biasv[16];

    const int g    = blockIdx.x;
    const int tid  = threadIdx.x;
    const int lane = tid & 63;
    const int wid  = tid >> 6;
    const int mt   = wid & 3;
    const int kg   = wid >> 2;

    const int n    = lane & 15;
    const int kq   = (lane >> 4) * 8;
    const int mrow = mt * 16 + (lane & 15);

    // --- load this wave's 12 W B-fragments once (gather from permuted W) ---
    bf16x8 wf[12];
    {
        const u16* Wg = wperm + (size_t)g * (kK * kNC);
        #pragma unroll
        for (int ks = 0; ks < 12; ++ks) {
            const int kb = kg * 384 + ks * 32 + kq;
            union { u16 u[8]; bf16x8 v; } tmp;
            #pragma unroll
            for (int j = 0; j < 8; ++j) tmp.u[j] = Wg[(size_t)(kb + j) * kNC + n];
            wf[ks] = tmp.v;
        }
    }

    if (tid < 256) cst[tid >> 2][tid & 3] = 0.f;
    if (tid < 16) {
        const int gate = tid >> 2, uu = tid & 3;
        biasv[tid] = bias[gate * kU + g * 4 + uu];
    }
    __syncthreads();

    for (int t = 0; t < kT; ++t) {
        const u16* hcur = hbuf + (size_t)(t & 1) * (kB * kU);
        const u16* xrow = xbf + ((size_t)t * kB + mrow) * kD;
        const u16* hrow = hcur + (size_t)mrow * kU;

        // --- MFMA over this wave's K slice: gates partial [16m x 16c] ---
        f32x4 acc = {0.f, 0.f, 0.f, 0.f};
        #pragma unroll
        for (int ks = 0; ks < 12; ++ks) {
            const int kb = kg * 384 + ks * 32;     // 32-chunk never straddles x/h split
            const u16* src = (kb < kD) ? (xrow + kb + kq) : (hrow + (kb - kD) + kq);
            bf16x8 af = *(const bf16x8*)src;
            acc = __builtin_amdgcn_mfma_f32_16x16x32_bf16(af, wf[ks], acc, 0, 0, 0);
        }

        // --- spill partials to LDS ---
        {
            const int col   = lane & 15;
            const int rbase = mt * 16 + (lane >> 4) * 4;
            #pragma unroll
            for (int r = 0; r < 4; ++r) part[kg][rbase + r][col] = acc[r];
        }
        __syncthreads();

        // --- reduce 4 K-partials + elementwise LSTM cell (threads 0..255) ---
        if (tid < 256) {
            const int m = tid >> 2, uu = tid & 3;
            float gv[4];
            #pragma unroll
            for (int gate = 0; gate < 4; ++gate) {
                const int c = gate * 4 + uu;
                gv[gate] = part[0][m][c] + part[1][m][c] +
                           part[2][m][c] + part[3][m][c] + biasv[c];
            }
            const float cold = cst[m][uu];
            const float si = 1.f / (1.f + __expf(-gv[0]));
            const float tj = tanhf(gv[1]);
            const float sf = 1.f / (1.f + __expf(-(gv[2] + 1.f)));  // forget_bias=1
            const float so = 1.f / (1.f + __expf(-gv[3]));
            const float cnew = cold * sf + si * tj;
            const float hnew = tanhf(cnew) * so;
            cst[m][uu] = cnew;

            const int u = g * 4 + uu;
            out[((size_t)m * kT + t) * kU + u] = hnew;
            u16* hnx = hbuf + (size_t)((t + 1) & 1) * (kB * kU);
            __bf16 hb = (__bf16)hnew;
            hnx[(size_t)m * kU + u] = *(u16*)&hb;
        }
        __syncthreads();

        // --- grid barrier (skip after last step) ---
        if (t + 1 < kT) {
            if (tid == 0) {
                __threadfence();  // agent-scope release: push h writes past XCD L2
                unsigned old = __hip_atomic_fetch_add(&barv[0], 1u,
                                   __ATOMIC_ACQ_REL, __HIP_MEMORY_SCOPE_AGENT);
                if (old == (unsigned)(kNG * (t + 1) - 1)) {
                    __hip_atomic_store(&barv[1], (unsigned)(t + 1),
                                       __ATOMIC_RELEASE, __HIP_MEMORY_SCOPE_AGENT);
                } else {
                    while (__hip_atomic_load(&barv[1], __ATOMIC_ACQUIRE,
                                             __HIP_MEMORY_SCOPE_AGENT) < (unsigned)(t + 1)) {
                        __builtin_amdgcn_s_sleep(2);
                    }
                }
                __threadfence();  // acquire: invalidate stale L1/L2 lines
            }
            __syncthreads();
        }
    }
}

extern "C" void kernel_launch(void* const* d_in, const int* in_sizes, int n_in,
                              void* d_out, int out_size, void* d_ws, size_t ws_size,
                              hipStream_t stream) {
    const float* inputs = (const float*)d_in[0];
    const float* kern   = (const float*)d_in[1];
    const float* bias   = (const float*)d_in[2];
    float* out = (float*)d_out;

    char* ws = (char*)d_ws;
    unsigned* barv = (unsigned*)(ws + OFF_BAR);
    u16* hbuf  = (u16*)(ws + OFF_H);
    u16* wperm = (u16*)(ws + OFF_W);
    u16* xbf   = (u16*)(ws + OFF_X);

    // zero barrier state + h0 (ws is re-poisoned to 0xAA before every call)
    hipMemsetAsync(ws, 0, OFF_W, stream);

    prep_w<<<dim3(kNG, kK / 16), 256, 0, stream>>>(kern, wperm);
    prep_x<<<(kT * kB * kD) / 256, 256, 0, stream>>>(inputs, xbf);

    const u16* wperm_c = wperm;
    const u16* xbf_c   = xbf;
    void* args[] = { (void*)&wperm_c, (void*)&xbf_c, (void*)&hbuf,
                     (void*)&bias, (void*)&out, (void*)&barv };
    hipLaunchCooperativeKernel((void*)lstm_persist, dim3(kNG), dim3(1024),
                               args, 0, stream);
}

// Round 2
// 13911.917 us; speedup vs baseline: 2.6470x; 2.6470x over previous
//
#include <hip/hip_runtime.h>

typedef unsigned short u16;
typedef unsigned long long u64;
typedef __bf16 bf16x8 __attribute__((ext_vector_type(8)));
typedef float f32x4 __attribute__((ext_vector_type(4)));

constexpr int kB = 64;       // batch
constexpr int kT = 1024;     // timesteps
constexpr int kD = 512;      // input dim
constexpr int kU = 1024;     // hidden units
constexpr int kK = kD + kU;  // 1536 total contraction
constexpr int kNG = 256;     // workgroups == column groups (4 u each)
constexpr int kNC = 16;      // gate columns per WG (4 u * 4 gates)

// ---- workspace layout (bytes) ----
constexpr size_t OFF_BAR = 0;                                  // counter @0, flag @128
constexpr size_t OFF_H   = 1024;                               // double-buffered h, bf16 [2][B][U]
constexpr size_t OFF_W   = OFF_H + 2ull * kB * kU * 2;         // permuted W bf16 [NG][K][NC]
constexpr size_t OFF_X   = OFF_W + (size_t)kNG * kK * kNC * 2; // x bf16 [T][B][D]

// ---------- prologue: permute + bf16-convert weights ----------
// Wperm[g][k][c] = kernel[k][ (c>>2)*U + g*4 + (c&3) ]
__global__ void prep_w(const float* __restrict__ kern, u16* __restrict__ wperm) {
    const int g = blockIdx.x;
    const int c = threadIdx.x & 15;
    const int k = blockIdx.y * 16 + (threadIdx.x >> 4);
    const int gate = c >> 2, uu = c & 3;
    float v = kern[(size_t)k * (4 * kU) + gate * kU + g * 4 + uu];
    __bf16 b = (__bf16)v;
    wperm[((size_t)g * kK + k) * kNC + c] = *(u16*)&b;
}

// ---------- prologue: transpose + bf16-convert inputs ----------
// xbf[t][b][d] = bf16(inputs[b][t][d])
__global__ void prep_x(const float* __restrict__ inp, u16* __restrict__ xbf) {
    const int idx = blockIdx.x * 256 + threadIdx.x;   // < T*B*D = 33554432
    const int d = idx & (kD - 1);
    const int r = idx >> 9;
    const int b = r & (kB - 1);
    const int t = r >> 6;
    float v = inp[((size_t)b * kT + t) * kD + d];
    __bf16 bb = (__bf16)v;
    xbf[idx] = *(u16*)&bb;
}

// ---------- persistent LSTM kernel ----------
// grid = 256 WGs (one per CU), block = 1024 threads (16 waves).
// wave wid: mt = wid&3 (16-row batch tile), kg = wid>>2 (384-wide K slice).
// h is exchanged through L3 via relaxed agent-scope atomics (sc1, L2-bypass)
// => NO buffer_wbl2 / buffer_inv cache maintenance; x/W stay warm in L2.
__global__ __launch_bounds__(1024) void lstm_persist(
        const u16* __restrict__ wperm,
        const u16* __restrict__ xbf,
        u16* __restrict__ hbuf,
        const float* __restrict__ bias,
        float* __restrict__ out,
        unsigned* __restrict__ barv)   // barv[0]=arrival cnt, barv[32]=epoch flag
{
    __shared__ float part[4][64][17];  // [kg][m][c], +1 pad vs bank conflicts
    __shared__ float cst[64][4];       // cell state c[m][uu], persistent in LDS
    __shared__ float biasv[16];

    const int g    = blockIdx.x;
    const int tid  = threadIdx.x;
    const int lane = tid & 63;
    const int wid  = tid >> 6;
    const int mt   = wid & 3;
    const int kg   = wid >> 2;

    const int n    = lane & 15;
    const int kq   = (lane >> 4) * 8;
    const int mrow = mt * 16 + (lane & 15);

    // --- load this wave's 12 W B-fragments once (gather from permuted W) ---
    bf16x8 wf[12];
    {
        const u16* Wg = wperm + (size_t)g * (kK * kNC);
        #pragma unroll
        for (int ks = 0; ks < 12; ++ks) {
            const int kb = kg * 384 + ks * 32 + kq;
            union { u16 u[8]; bf16x8 v; } tmp;
            #pragma unroll
            for (int j = 0; j < 8; ++j) tmp.u[j] = Wg[(size_t)(kb + j) * kNC + n];
            wf[ks] = tmp.v;
        }
    }

    if (tid < 256) cst[tid >> 2][tid & 3] = 0.f;
    if (tid < 16) {
        const int gate = tid >> 2, uu = tid & 3;
        biasv[tid] = bias[gate * kU + g * 4 + uu];
    }
    __syncthreads();

    for (int t = 0; t < kT; ++t) {
        const u16* hcur = hbuf + (size_t)(t & 1) * (kB * kU);
        const u16* xrow = xbf + ((size_t)t * kB + mrow) * kD;
        const u16* hrow = hcur + (size_t)mrow * kU;

        // --- phase 1: gather all 12 A-fragments (x cached; h via sc1 atomics) ---
        bf16x8 af[12];
        #pragma unroll
        for (int ks = 0; ks < 12; ++ks) {
            const int kb = kg * 384 + ks * 32;   // 32-chunk never straddles x/h split
            if (kb < kD) {
                af[ks] = *(const bf16x8*)(xrow + kb + kq);
            } else {
                u64* hp = (u64*)(hrow + (kb - kD) + kq);
                union { u64 q[2]; bf16x8 v; } tmp;
                tmp.q[0] = __hip_atomic_load(hp,     __ATOMIC_RELAXED, __HIP_MEMORY_SCOPE_AGENT);
                tmp.q[1] = __hip_atomic_load(hp + 1, __ATOMIC_RELAXED, __HIP_MEMORY_SCOPE_AGENT);
                af[ks] = tmp.v;
            }
        }

        // --- phase 2: MFMA chain over this wave's K slice ---
        f32x4 acc = {0.f, 0.f, 0.f, 0.f};
        #pragma unroll
        for (int ks = 0; ks < 12; ++ks)
            acc = __builtin_amdgcn_mfma_f32_16x16x32_bf16(af[ks], wf[ks], acc, 0, 0, 0);

        // --- spill partials to LDS ---
        {
            const int col   = lane & 15;
            const int rbase = mt * 16 + (lane >> 4) * 4;
            #pragma unroll
            for (int r = 0; r < 4; ++r) part[kg][rbase + r][col] = acc[r];
        }
        __syncthreads();

        // --- reduce 4 K-partials + elementwise LSTM cell (threads 0..255) ---
        if (tid < 256) {
            const int m = tid >> 2, uu = tid & 3;
            float gv[4];
            #pragma unroll
            for (int gate = 0; gate < 4; ++gate) {
                const int c = gate * 4 + uu;
                gv[gate] = part[0][m][c] + part[1][m][c] +
                           part[2][m][c] + part[3][m][c] + biasv[c];
            }
            const float cold = cst[m][uu];
            const float si = 1.f / (1.f + __expf(-gv[0]));
            const float tj = tanhf(gv[1]);
            const float sf = 1.f / (1.f + __expf(-(gv[2] + 1.f)));  // forget_bias=1
            const float so = 1.f / (1.f + __expf(-gv[3]));
            const float cnew = cold * sf + si * tj;
            const float hnew = tanhf(cnew) * so;
            cst[m][uu] = cnew;

            const int u = g * 4 + uu;
            out[((size_t)m * kT + t) * kU + u] = hnew;

            // pack 2 adjacent bf16 h-values, even threads store u32 via sc1 atomic
            __bf16 hb = (__bf16)hnew;
            unsigned hbits = (unsigned)*(u16*)&hb;
            unsigned nbits = __shfl_down(hbits, 1);
            if ((tid & 1) == 0) {
                unsigned packed = hbits | (nbits << 16);
                u16* hnx = hbuf + (size_t)((t + 1) & 1) * (kB * kU);
                unsigned* dst = (unsigned*)hnx + ((size_t)m * kU + u) / 2;
                __hip_atomic_store(dst, packed, __ATOMIC_RELAXED, __HIP_MEMORY_SCOPE_AGENT);
            }
        }
        // drains vmcnt for every wave => all h stores visible at L3 before arrival
        __syncthreads();

        // --- grid barrier, all-relaxed (no cache maintenance) ---
        if (t + 1 < kT) {
            if (tid == 0) {
                unsigned old = __hip_atomic_fetch_add(&barv[0], 1u,
                                   __ATOMIC_RELAXED, __HIP_MEMORY_SCOPE_AGENT);
                if (old == (unsigned)(kNG * (t + 1) - 1)) {
                    __hip_atomic_store(&barv[32], (unsigned)(t + 1),
                                       __ATOMIC_RELAXED, __HIP_MEMORY_SCOPE_AGENT);
                } else {
                    while (__hip_atomic_load(&barv[32], __ATOMIC_RELAXED,
                                             __HIP_MEMORY_SCOPE_AGENT) < (unsigned)(t + 1)) {
                        __builtin_amdgcn_s_sleep(2);
                    }
                }
            }
            __syncthreads();
        }
    }
}

extern "C" void kernel_launch(void* const* d_in, const int* in_sizes, int n_in,
                              void* d_out, int out_size, void* d_ws, size_t ws_size,
                              hipStream_t stream) {
    const float* inputs = (const float*)d_in[0];
    const float* kern   = (const float*)d_in[1];
    const float* bias   = (const float*)d_in[2];
    float* out = (float*)d_out;

    char* ws = (char*)d_ws;
    unsigned* barv = (unsigned*)(ws + OFF_BAR);
    u16* hbuf  = (u16*)(ws + OFF_H);
    u16* wperm = (u16*)(ws + OFF_W);
    u16* xbf   = (u16*)(ws + OFF_X);

    // zero barrier state + h0 (ws is re-poisoned to 0xAA before every call)
    hipMemsetAsync(ws, 0, OFF_W, stream);

    prep_w<<<dim3(kNG, kK / 16), 256, 0, stream>>>(kern, wperm);
    prep_x<<<(kT * kB * kD) / 256, 256, 0, stream>>>(inputs, xbf);

    const u16* wperm_c = wperm;
    const u16* xbf_c   = xbf;
    void* args[] = { (void*)&wperm_c, (void*)&xbf_c, (void*)&hbuf,
                     (void*)&bias, (void*)&out, (void*)&barv };
    hipLaunchCooperativeKernel((void*)lstm_persist, dim3(kNG), dim3(1024),
                               args, 0, stream);
}